// Round 1
// baseline (2315.253 us; speedup 1.0000x reference)
//
#include <hip/hip_runtime.h>

#define NENT 40000
#define NB 128
#define NHID 128
#define NOPS 12
#define EPO 300000
#define NTOT (NOPS * EPO)
#define NRANK 3
#define NSTEP 3

// ---------------- CSR build ----------------
__global__ void hist_kernel(const int* __restrict__ keys, int* __restrict__ cnt) {
    int i = blockIdx.x * 256 + threadIdx.x;
    if (i < NTOT) atomicAdd(&cnt[keys[i]], 1);
}

__global__ void scan_kernel(const int* __restrict__ cnt, int* __restrict__ rp) {
    __shared__ int part[1024];
    int t = threadIdx.x;
    int beg = t * 40;
    int end = min(NENT, beg + 40);
    int s = 0;
    for (int i = beg; i < end; ++i) s += cnt[i];
    part[t] = s;
    __syncthreads();
    for (int offs = 1; offs < 1024; offs <<= 1) {
        int add = (t >= offs) ? part[t - offs] : 0;
        __syncthreads();
        part[t] += add;
        __syncthreads();
    }
    int run = part[t] - s;  // exclusive prefix at chunk start
    for (int i = beg; i < end; ++i) { rp[i] = run; run += cnt[i]; }
    if (t == 1023) rp[NENT] = part[1023];
}

__global__ void scatter_kernel(const int* __restrict__ keys, const int* __restrict__ others,
                               const float* __restrict__ vals, const int* __restrict__ rp,
                               int* __restrict__ fill, int2* __restrict__ edges) {
    int i = blockIdx.x * 256 + threadIdx.x;
    if (i < NTOT) {
        int key = keys[i];
        int pos = atomicAdd(&fill[key], 1);
        int op = i / EPO;  // compile-time magic-mul
        edges[rp[key] + pos] = make_int2(others[i] | (op << 16), __float_as_int(vals[i]));
    }
}

// ---------------- LSTM ----------------
// zx[combo=dir*3+r][b][g] = emb[queries[b]] . Wih[r][g] + bih[r][g] + bhh[r][g]
__global__ void zx_kernel(const int* __restrict__ queries, const float* __restrict__ emb,
                          const float* __restrict__ Wih_f, const float* __restrict__ bih_f,
                          const float* __restrict__ bhh_f,
                          const float* __restrict__ Wih_b, const float* __restrict__ bih_b,
                          const float* __restrict__ bhh_b,
                          float* __restrict__ zx) {
    int combo = blockIdx.x >> 7;
    int b = blockIdx.x & 127;
    int dir = combo / 3, r = combo % 3;
    const float* Wih = (dir ? Wih_b : Wih_f) + r * 512 * 128;
    const float* bih = (dir ? bih_b : bih_f) + r * 512;
    const float* bhh = (dir ? bhh_b : bhh_f) + r * 512;
    __shared__ float x[128];
    int u = threadIdx.x;
    x[u] = emb[queries[b] * 128 + u];
    __syncthreads();
    const float* W0p = Wih + u * 128;
    const float* W1p = Wih + (128 + u) * 128;
    const float* W2p = Wih + (256 + u) * 128;
    const float* W3p = Wih + (384 + u) * 128;
    float a0 = 0.f, a1 = 0.f, a2 = 0.f, a3 = 0.f;
    for (int d = 0; d < 128; ++d) {
        float xv = x[d];
        a0 = fmaf(xv, W0p[d], a0);
        a1 = fmaf(xv, W1p[d], a1);
        a2 = fmaf(xv, W2p[d], a2);
        a3 = fmaf(xv, W3p[d], a3);
    }
    float* o = zx + (size_t)(combo * 128 + b) * 512;
    o[u]       = a0 + bih[u]       + bhh[u];
    o[128 + u] = a1 + bih[128 + u] + bhh[128 + u];
    o[256 + u] = a2 + bih[256 + u] + bhh[256 + u];
    o[384 + u] = a3 + bih[384 + u] + bhh[384 + u];
}

// one step of all 6 (dir,rank) chains; hstate slot s = state after s+1 steps
__global__ void lstm_step_kernel(const float* __restrict__ Whh_f, const float* __restrict__ Whh_b,
                                 const float* __restrict__ zx, float* __restrict__ hstate,
                                 float* __restrict__ cstate, int s) {
    int combo = blockIdx.x >> 7;
    int b = blockIdx.x & 127;
    int dir = combo / 3, r = combo % 3;
    const float* Whh = (dir ? Whh_b : Whh_f) + r * 512 * 128;
    __shared__ float h[128];
    int u = threadIdx.x;
    float cp;
    if (s == 0) { h[u] = 0.f; cp = 0.f; }
    else {
        h[u] = hstate[(size_t)((combo * 3 + (s - 1)) * 128 + b) * 128 + u];
        cp = cstate[(size_t)(combo * 128 + b) * 128 + u];
    }
    __syncthreads();
    const float* Wi = Whh + u * 128;
    const float* Wf = Whh + (128 + u) * 128;
    const float* Wg = Whh + (256 + u) * 128;
    const float* Wo = Whh + (384 + u) * 128;
    float a0 = 0.f, a1 = 0.f, a2 = 0.f, a3 = 0.f;
    for (int d = 0; d < 128; ++d) {
        float hv = h[d];
        a0 = fmaf(hv, Wi[d], a0);
        a1 = fmaf(hv, Wf[d], a1);
        a2 = fmaf(hv, Wg[d], a2);
        a3 = fmaf(hv, Wo[d], a3);
    }
    const float* z = zx + (size_t)(combo * 128 + b) * 512;
    float zi = z[u] + a0, zf = z[128 + u] + a1, zg = z[256 + u] + a2, zo = z[384 + u] + a3;
    float ig = 1.f / (1.f + expf(-zi));
    float fg = 1.f / (1.f + expf(-zf));
    float gg = tanhf(zg);
    float og = 1.f / (1.f + expf(-zo));
    float cn = fg * cp + ig * gg;
    float hn = og * tanhf(cn);
    cstate[(size_t)(combo * 128 + b) * 128 + u] = cn;
    hstate[(size_t)((combo * 3 + s) * 128 + b) * 128 + u] = hn;
}

// attn[r][t][k][b] = softmax_k( concat(hf_{t+1}, hb_{3-t}) @ W0 + b0 )
__global__ void attn_kernel(const float* __restrict__ hstate, const float* __restrict__ W0,
                            const float* __restrict__ b0, float* __restrict__ attn) {
    int r = blockIdx.x / 3, t = blockIdx.x % 3;
    __shared__ float W0s[256 * 13];
    for (int idx = threadIdx.x; idx < 256 * 13; idx += 128) W0s[idx] = W0[idx];
    __syncthreads();
    int b = threadIdx.x;
    float acc[13];
    for (int k = 0; k < 13; ++k) acc[k] = b0[k];
    const float* hf = hstate + (size_t)(((0 * 3 + r) * 3 + t) * 128 + b) * 128;
    const float* hb = hstate + (size_t)(((1 * 3 + r) * 3 + (2 - t)) * 128 + b) * 128;
    for (int u = 0; u < 128; ++u) {
        float v = hf[u];
        for (int k = 0; k < 13; ++k) acc[k] = fmaf(v, W0s[u * 13 + k], acc[k]);
    }
    for (int u = 0; u < 128; ++u) {
        float v = hb[u];
        for (int k = 0; k < 13; ++k) acc[k] = fmaf(v, W0s[(128 + u) * 13 + k], acc[k]);
    }
    float m = acc[0];
    for (int k = 1; k < 13; ++k) m = fmaxf(m, acc[k]);
    float e[13];
    float sum = 0.f;
    for (int k = 0; k < 13; ++k) { e[k] = expf(acc[k] - m); sum += e[k]; }
    float inv = 1.f / sum;
    float* ao = attn + (size_t)(r * 3 + t) * 13 * 128;
    for (int k = 0; k < 13; ++k) ao[k * 128 + b] = e[k] * inv;
}

// ---------------- steps 0+1 fused, sparse (memory starts one-hot; step is linear) ----------------
__global__ void fused01_kernel(const int* __restrict__ heads, const float* __restrict__ attn,
                               const int* __restrict__ rpS, const int2* __restrict__ edgesS,
                               float* __restrict__ mem2) {
    int r = blockIdx.y;
    int b = blockIdx.x;
    __shared__ float c0s[13], c1s[13];
    if (threadIdx.x < 13) {
        c0s[threadIdx.x] = attn[(size_t)((r * 3 + 0) * 13 + threadIdx.x) * 128 + b];
        c1s[threadIdx.x] = attn[(size_t)((r * 3 + 1) * 13 + threadIdx.x) * 128 + b];
    }
    __syncthreads();
    int h = heads[b];
    int beg = rpS[h], end = rpS[h + 1];
    int nE = end - beg + 1;   // +1 for the identity entry of step 0
    float* mem = mem2 + (size_t)r * NENT * 128 + b;
    for (int ent = threadIdx.x; ent < nE; ent += 128) {
        int i; float wv;
        if (ent == 0) { i = h; wv = c0s[12]; }
        else {
            int2 e = edgesS[beg + ent - 1];
            i = e.x & 0xFFFF;
            wv = __int_as_float(e.y) * c0s[e.x >> 16];
        }
        // step-1 identity
        atomicAdd(&mem[(size_t)i * 128], c1s[12] * wv);
        // step-1 out-edge expansion
        int fb = rpS[i], fe = rpS[i + 1];
        for (int f = fb; f < fe; ++f) {
            int2 e2 = edgesS[f];
            atomicAdd(&mem[(size_t)(e2.x & 0xFFFF) * 128],
                      __int_as_float(e2.y) * c1s[e2.x >> 16] * wv);
        }
    }
}

// ---------------- step 2, dense gather (wave per row, float2 per lane) ----------------
__global__ void dense_step_kernel(const float* __restrict__ attn, const int* __restrict__ rpD,
                                  const int2* __restrict__ edgesD, const float* __restrict__ in,
                                  float* __restrict__ out) {
    int r = blockIdx.y;
    __shared__ float cs[13 * 128];
    for (int idx = threadIdx.x; idx < 13 * 128; idx += 256)
        cs[idx] = attn[(size_t)((r * 3 + 2) * 13) * 128 + idx];
    __syncthreads();
    int lane = threadIdx.x & 63;
    int wave = threadIdx.x >> 6;
    int bb = lane * 2;
    const float* inr = in + (size_t)r * NENT * 128;
    float* outr = out + (size_t)r * NENT * 128;
    int base = blockIdx.x * 32 + wave * 8;
    float2 cid = *(const float2*)&cs[12 * 128 + bb];
    for (int jj = 0; jj < 8; ++jj) {
        int j = base + jj;
        int kb = rpD[j], ke = rpD[j + 1];
        float2 mi = *(const float2*)(inr + (size_t)j * 128 + bb);
        float2 acc;
        acc.x = cid.x * mi.x;
        acc.y = cid.y * mi.y;
        for (int k = kb; k < ke; ++k) {
            int2 e = edgesD[k];
            int src = e.x & 0xFFFF;
            int op = e.x >> 16;
            float v = __int_as_float(e.y);
            float2 mm = *(const float2*)(inr + (size_t)src * 128 + bb);
            float2 cc = *(const float2*)&cs[op * 128 + bb];
            acc.x = fmaf(v * cc.x, mm.x, acc.x);
            acc.y = fmaf(v * cc.y, mm.y, acc.y);
        }
        *(float2*)(outr + (size_t)j * 128 + bb) = acc;
    }
}

// ---------------- epilogue ----------------
__global__ void norm_kernel(const float* __restrict__ mem3, float* __restrict__ normv) {
    int r = blockIdx.y;
    int b = threadIdx.x & 127;
    int jo = threadIdx.x >> 7;
    int j0 = blockIdx.x * 64;
    const float* m = mem3 + (size_t)r * NENT * 128;
    float acc = 0.f;
    for (int jj = jo; jj < 64; jj += 2)
        acc += m[(size_t)(j0 + jj) * 128 + b];
    atomicAdd(&normv[r * 128 + b], acc);
}

__global__ void rnorm_kernel(const float* __restrict__ normv, float* __restrict__ rnormv) {
    int i = threadIdx.x;
    rnormv[i] = 1.f / fmaxf(normv[i], 1e-20f);
}

__global__ void final_kernel(const float* __restrict__ mem3, const float* __restrict__ rnormv,
                             float* __restrict__ out) {
    __shared__ float tile[32 * 129];
    __shared__ float rn[384];
    for (int idx = threadIdx.x; idx < 384; idx += 256) rn[idx] = rnormv[idx];
    __syncthreads();
    int j0 = blockIdx.x * 32;
    for (int it = 0; it < 16; ++it) {
        int lin = it * 256 + threadIdx.x;
        int jj = lin >> 7, b = lin & 127;
        float s = 0.f;
        for (int r = 0; r < 3; ++r)
            s += mem3[((size_t)r * NENT + j0 + jj) * 128 + b] * rn[r * 128 + b];
        tile[jj * 129 + b] = s;
    }
    __syncthreads();
    for (int it = 0; it < 16; ++it) {
        int lin = it * 256 + threadIdx.x;
        int b = lin >> 5, jj = lin & 31;
        out[(size_t)b * NENT + j0 + jj] = tile[jj * 129 + b];
    }
}

extern "C" void kernel_launch(void* const* d_in, const int* in_sizes, int n_in,
                              void* d_out, int out_size, void* d_ws, size_t ws_size,
                              hipStream_t stream) {
    const int*   queries  = (const int*)d_in[0];
    const int*   heads    = (const int*)d_in[1];
    const int*   edge_src = (const int*)d_in[2];
    const int*   edge_dst = (const int*)d_in[3];
    const float* edge_val = (const float*)d_in[4];
    const float* emb      = (const float*)d_in[5];
    const float* Wih_f    = (const float*)d_in[6];
    const float* Whh_f    = (const float*)d_in[7];
    const float* bih_f    = (const float*)d_in[8];
    const float* bhh_f    = (const float*)d_in[9];
    const float* Wih_b    = (const float*)d_in[10];
    const float* Whh_b    = (const float*)d_in[11];
    const float* bih_b    = (const float*)d_in[12];
    const float* bhh_b    = (const float*)d_in[13];
    const float* W0       = (const float*)d_in[14];
    const float* b0       = (const float*)d_in[15];
    float* out = (float*)d_out;

    char* w = (char*)d_ws;
    size_t off = 0;
    auto alloc = [&](size_t bytes) -> void* {
        off = (off + 255) & ~(size_t)255;
        void* p = w + off;
        off += bytes;
        return p;
    };
    float* attn   = (float*)alloc((size_t)NRANK * NSTEP * 13 * NB * sizeof(float));
    float* zx     = (float*)alloc((size_t)6 * NB * 512 * sizeof(float));
    float* hstate = (float*)alloc((size_t)6 * 3 * NB * NHID * sizeof(float));
    float* cstate = (float*)alloc((size_t)6 * NB * NHID * sizeof(float));
    int*   rpS    = (int*)alloc((size_t)(NENT + 1) * sizeof(int));
    int*   rpD    = (int*)alloc((size_t)(NENT + 1) * sizeof(int));
    int*   cnt    = (int*)alloc((size_t)NENT * sizeof(int));
    int2*  edgesS = (int2*)alloc((size_t)NTOT * sizeof(int2));
    int2*  edgesD = (int2*)alloc((size_t)NTOT * sizeof(int2));
    float* mem2   = (float*)alloc((size_t)NRANK * NENT * NB * sizeof(float));
    float* mem3   = (float*)alloc((size_t)NRANK * NENT * NB * sizeof(float));
    float* normv  = (float*)alloc((size_t)NRANK * NB * sizeof(float));
    float* rnormv = (float*)alloc((size_t)NRANK * NB * sizeof(float));

    int histGrid = (NTOT + 255) / 256;

    // CSR by src (for sparse steps 0+1)
    hipMemsetAsync(cnt, 0, NENT * sizeof(int), stream);
    hist_kernel<<<histGrid, 256, 0, stream>>>(edge_src, cnt);
    scan_kernel<<<1, 1024, 0, stream>>>(cnt, rpS);
    hipMemsetAsync(cnt, 0, NENT * sizeof(int), stream);
    scatter_kernel<<<histGrid, 256, 0, stream>>>(edge_src, edge_dst, edge_val, rpS, cnt, edgesS);

    // CSR by dst (for dense step 2)
    hipMemsetAsync(cnt, 0, NENT * sizeof(int), stream);
    hist_kernel<<<histGrid, 256, 0, stream>>>(edge_dst, cnt);
    scan_kernel<<<1, 1024, 0, stream>>>(cnt, rpD);
    hipMemsetAsync(cnt, 0, NENT * sizeof(int), stream);
    scatter_kernel<<<histGrid, 256, 0, stream>>>(edge_dst, edge_src, edge_val, rpD, cnt, edgesD);

    // LSTM + attention
    zx_kernel<<<768, 128, 0, stream>>>(queries, emb, Wih_f, bih_f, bhh_f, Wih_b, bih_b, bhh_b, zx);
    for (int s = 0; s < 3; ++s)
        lstm_step_kernel<<<768, 128, 0, stream>>>(Whh_f, Whh_b, zx, hstate, cstate, s);
    attn_kernel<<<9, 128, 0, stream>>>(hstate, W0, b0, attn);

    // steps 0+1 (sparse), step 2 (dense)
    hipMemsetAsync(mem2, 0, (size_t)NRANK * NENT * NB * sizeof(float), stream);
    {
        dim3 g(NB, NRANK);
        fused01_kernel<<<g, 128, 0, stream>>>(heads, attn, rpS, edgesS, mem2);
    }
    {
        dim3 g(NENT / 32, NRANK);
        dense_step_kernel<<<g, 256, 0, stream>>>(attn, rpD, edgesD, mem2, mem3);
    }

    // normalize + transpose-accumulate into (B, E) output
    hipMemsetAsync(normv, 0, NRANK * NB * sizeof(float), stream);
    {
        dim3 g(NENT / 64, NRANK);
        norm_kernel<<<g, 256, 0, stream>>>(mem3, normv);
    }
    rnorm_kernel<<<1, NRANK * NB, 0, stream>>>(normv, rnormv);
    final_kernel<<<NENT / 32, 256, 0, stream>>>(mem3, rnormv, out);
}